// Round 2
// baseline (384.315 us; speedup 1.0000x reference)
//
#include <hip/hip_runtime.h>
#include <hip/hip_fp16.h>

#define HIDDEN 128
#define P_NUM 8
#define PLEN 4
#define ETYPES 2
#define BN 32                      // nodes per gemm block (100000 = 3125*32)
#define AP 136                     // bf16 row pitch in LDS
#define NCHUNK 8                   // 8 chunks x 16 dims = 128 output dims
#define REC 32                     // bytes per (node,chunk) record: 16 per type

typedef __attribute__((ext_vector_type(8))) short short8;
typedef __attribute__((ext_vector_type(4))) float floatx4;
typedef __attribute__((ext_vector_type(4))) int intx4;

__device__ __forceinline__ unsigned short f2bf(float x) {
  unsigned int u = __float_as_uint(x);
  u += 0x7FFFu + ((u >> 16) & 1u);
  return (unsigned short)(u >> 16);
}

// generic f32 -> bf16 (used for W_fc)
__global__ __launch_bounds__(256) void cvt_bf16(const float* __restrict__ in,
                                                unsigned short* __restrict__ out, int n4) {
  int i = blockIdx.x * blockDim.x + threadIdx.x;
  if (i < n4) {
    float4 f = ((const float4*)in)[i];
    ((ushort4*)out)[i] = make_ushort4(f2bf(f.x), f2bf(f.y), f2bf(f.z), f2bf(f.w));
  }
}

// ---- Kernel A: Y = feats @ [W0^T | W1^T] (N x 256), fused u8 quant, CHUNKED output ----
// Yc[c][node][t*16 + k] = biased-u8 of Y[node][t*128 + c*16 + k]; sYh[node] = half2(s0, s1).
__global__ __launch_bounds__(256, 4) void gemm_quant(
    const float* __restrict__ feats,
    const unsigned short* __restrict__ wfc_bf,   // bf16, 128 x 256
    unsigned char* __restrict__ Yc,              // u8, NCHUNK x N x REC
    unsigned short* __restrict__ sYh,            // fp16 bits, N x 2
    int n_nodes)
{
  __shared__ __align__(16) unsigned short Abf[BN * AP];   // 8704 B; overlaid by u8 bounce later
  __shared__ float rowmax[ETYPES][2][BN];

  const int tid = threadIdx.x;
  const int n0 = blockIdx.x * BN;

  // stage feats f32 -> bf16 LDS (16 elems / thread)
  {
    const int row = tid >> 3;
    const int c0 = (tid & 7) * 16;
    int rg = n0 + row; if (rg >= n_nodes) rg = n_nodes - 1;
    const float* src = feats + (size_t)rg * HIDDEN + c0;
    float4 v0 = ((const float4*)src)[0];
    float4 v1 = ((const float4*)src)[1];
    float4 v2 = ((const float4*)src)[2];
    float4 v3 = ((const float4*)src)[3];
    short8 u0, u1;
    u0[0]=(short)f2bf(v0.x); u0[1]=(short)f2bf(v0.y); u0[2]=(short)f2bf(v0.z); u0[3]=(short)f2bf(v0.w);
    u0[4]=(short)f2bf(v1.x); u0[5]=(short)f2bf(v1.y); u0[6]=(short)f2bf(v1.z); u0[7]=(short)f2bf(v1.w);
    u1[0]=(short)f2bf(v2.x); u1[1]=(short)f2bf(v2.y); u1[2]=(short)f2bf(v2.z); u1[3]=(short)f2bf(v2.w);
    u1[4]=(short)f2bf(v3.x); u1[5]=(short)f2bf(v3.y); u1[6]=(short)f2bf(v3.z); u1[7]=(short)f2bf(v3.w);
    *(short8*)&Abf[row * AP + c0] = u0;
    *(short8*)&Abf[row * AP + c0 + 8] = u1;
  }
  __syncthreads();

  const int wv = tid >> 6, lane = tid & 63, q = lane >> 4, rr = lane & 15;

  floatx4 acc[2][4];
  #pragma unroll
  for (int mt = 0; mt < 2; ++mt)
    #pragma unroll
    for (int jt = 0; jt < 4; ++jt)
      acc[mt][jt] = (floatx4){0.f, 0.f, 0.f, 0.f};

  // wave wv owns output cols j = wv*64 + jt*16 + rr  (j in [0,256))
  #pragma unroll
  for (int kk = 0; kk < 4; ++kk) {
    short8 af[2];
    af[0] = *(const short8*)&Abf[rr * AP + kk * 32 + q * 8];
    af[1] = *(const short8*)&Abf[(16 + rr) * AP + kk * 32 + q * 8];
    #pragma unroll
    for (int jt = 0; jt < 4; ++jt) {
      const int j = wv * 64 + jt * 16 + rr;
      const short8 bf = *(const short8*)&wfc_bf[(size_t)(j & 127) * (ETYPES * HIDDEN)
                                                + (j >> 7) * HIDDEN + kk * 32 + q * 8];
      acc[0][jt] = __builtin_amdgcn_mfma_f32_16x16x32_bf16(af[0], bf, acc[0][jt], 0, 0, 0);
      acc[1][jt] = __builtin_amdgcn_mfma_f32_16x16x32_bf16(af[1], bf, acc[1][jt], 0, 0, 0);
    }
  }

  // --- per-(node,half) absmax ---
  const int e = wv >> 1;
  float mx[2][4];
  #pragma unroll
  for (int mt = 0; mt < 2; ++mt)
    #pragma unroll
    for (int reg = 0; reg < 4; ++reg)
      mx[mt][reg] = fmaxf(fmaxf(fabsf(acc[mt][0][reg]), fabsf(acc[mt][1][reg])),
                          fmaxf(fabsf(acc[mt][2][reg]), fabsf(acc[mt][3][reg])));
  #pragma unroll
  for (int d = 1; d < 16; d <<= 1)
    #pragma unroll
    for (int mt = 0; mt < 2; ++mt)
      #pragma unroll
      for (int reg = 0; reg < 4; ++reg)
        mx[mt][reg] = fmaxf(mx[mt][reg], __shfl_xor(mx[mt][reg], d));
  if (rr == 0) {
    #pragma unroll
    for (int mt = 0; mt < 2; ++mt)
      #pragma unroll
      for (int reg = 0; reg < 4; ++reg)
        rowmax[e][wv & 1][mt * 16 + q * 4 + reg] = mx[mt][reg];
  }
  __syncthreads();   // fences Abf reads before u8 overlay

  // u8 bounce, XOR-swizzled by node (16B-block index ^ (node&7)) to kill copyout bank conflicts
  unsigned char* Yb = (unsigned char*)Abf;   // 32 x 256 u8 (8 KB)
  #pragma unroll
  for (int mt = 0; mt < 2; ++mt)
    #pragma unroll
    for (int reg = 0; reg < 4; ++reg) {
      const int node = mt * 16 + q * 4 + reg;
      const float full = fmaxf(rowmax[e][0][node], rowmax[e][1][node]);
      const float inv = (full > 0.f) ? 127.f * __builtin_amdgcn_rcpf(full) : 0.f;
      #pragma unroll
      for (int jt = 0; jt < 4; ++jt) {
        const int u = (int)rintf(acc[mt][jt][reg] * inv) + 128;
        const int col = wv * 64 + jt * 16 + rr;
        Yb[node * 256 + (col ^ ((node & 7) << 4))] = (unsigned char)u;
      }
      if (rr == 0 && (wv & 1) == 0 && (n0 + node) < n_nodes)
        sYh[(size_t)(n0 + node) * ETYPES + e] =
            __half_as_ushort(__float2half(full * (1.f / 127.f)));
    }
  __syncthreads();

  // chunked copyout: thread -> (chunk cc, local node nl); 16B per type
  {
    const int cc = tid >> 5, nl = tid & 31;
    if (n0 + nl < n_nodes) {
      const int sw = (nl & 7) << 4;
      uint4 r0 = *(const uint4*)&Yb[nl * 256 + ((cc * 16) ^ sw)];
      uint4 r1 = *(const uint4*)&Yb[nl * 256 + ((128 + cc * 16) ^ sw)];
      unsigned char* dst = Yc + ((size_t)cc * n_nodes + (n0 + nl)) * REC;
      *(uint4*)dst = r0;
      *(uint4*)(dst + 16) = r1;
    }
  }
}

// ---- Kernel B: chunked gather. Each lane owns one (node, chunk): 32 gathers x 16 B,
// 16-dim register accumulator, zero LDS, zero cross-lane ops. Chunk = blockIdx&7 so each
// XCD's L2 holds one 3.2 MB chunk region (+0.4 MB scales) -> gathers are L2 hits. ----
__global__ __launch_bounds__(256, 6) void impeller_gather(
    const unsigned char* __restrict__ Yc,
    const unsigned short* __restrict__ sYh,   // fp16 bits, N x 2
    const int* __restrict__ paths,
    const int* __restrict__ ptypes,
    const float* __restrict__ pweights,
    float* __restrict__ out,
    int n_nodes)
{
  const int c = blockIdx.x & (NCHUNK - 1);
  const int nb = blockIdx.x >> 3;
  const int node = nb * 256 + threadIdx.x;
  if (node >= n_nodes) return;

  int tmask = 0, cnt0 = 0;
  #pragma unroll
  for (int p = 0; p < P_NUM; ++p) { int t = ptypes[p]; tmask |= (t & 1) << p; cnt0 += (t == 0); }
  const int cnt1 = P_NUM - cnt0;
  const float ic0 = cnt0 ? 1.f / (float)cnt0 : 0.f;
  const float ic1 = cnt1 ? 1.f / (float)cnt1 : 0.f;
  float w0[PLEN], w1[PLEN];
  #pragma unroll
  for (int l = 0; l < PLEN; ++l) {
    w0[l] = pweights[l] * ic0;
    w1[l] = pweights[PLEN + l] * ic1;
  }

  const unsigned char* basec = Yc + (size_t)c * n_nodes * REC;
  float acc[16];
  #pragma unroll
  for (int k = 0; k < 16; ++k) acc[k] = 0.f;
  float corr = 0.f;

  #pragma unroll 2
  for (int p = 0; p < P_NUM; ++p) {
    const intx4 iv = __builtin_nontemporal_load(
        (const intx4*)(paths + ((size_t)p * n_nodes + node) * PLEN));
    const int tp = (tmask >> p) & 1;
    const int toff = tp << 4;
    #pragma unroll
    for (int l = 0; l < PLEN; ++l) {
      const int idx = iv[l];
      const uint4 f = *(const uint4*)(basec + (size_t)idx * REC + toff);
      const float s = __half2float(((const __half*)sYh)[idx * 2 + tp]);
      const float cs = (tp ? w1[l] : w0[l]) * s;
      corr += cs;
      acc[0]  += cs * (float)( f.x        & 0xFFu);
      acc[1]  += cs * (float)((f.x >>  8) & 0xFFu);
      acc[2]  += cs * (float)((f.x >> 16) & 0xFFu);
      acc[3]  += cs * (float)( f.x >> 24        );
      acc[4]  += cs * (float)( f.y        & 0xFFu);
      acc[5]  += cs * (float)((f.y >>  8) & 0xFFu);
      acc[6]  += cs * (float)((f.y >> 16) & 0xFFu);
      acc[7]  += cs * (float)( f.y >> 24        );
      acc[8]  += cs * (float)( f.z        & 0xFFu);
      acc[9]  += cs * (float)((f.z >>  8) & 0xFFu);
      acc[10] += cs * (float)((f.z >> 16) & 0xFFu);
      acc[11] += cs * (float)( f.z >> 24        );
      acc[12] += cs * (float)( f.w        & 0xFFu);
      acc[13] += cs * (float)((f.w >>  8) & 0xFFu);
      acc[14] += cs * (float)((f.w >> 16) & 0xFFu);
      acc[15] += cs * (float)( f.w >> 24        );
    }
  }

  const float b = 128.f * corr;
  float* op = out + (size_t)node * HIDDEN + c * 16;
  #pragma unroll
  for (int k = 0; k < 4; ++k) {
    floatx4 o;
    o[0] = fmaxf(acc[4 * k + 0] - b, 0.f);
    o[1] = fmaxf(acc[4 * k + 1] - b, 0.f);
    o[2] = fmaxf(acc[4 * k + 2] - b, 0.f);
    o[3] = fmaxf(acc[4 * k + 3] - b, 0.f);
    __builtin_nontemporal_store(o, (floatx4*)(op + 4 * k));
  }
}

extern "C" void kernel_launch(void* const* d_in, const int* in_sizes, int n_in,
                              void* d_out, int out_size, void* d_ws, size_t ws_size,
                              hipStream_t stream) {
  const float* feats    = (const float*)d_in[0];
  const int*   paths    = (const int*)d_in[1];
  const int*   ptypes   = (const int*)d_in[2];
  const float* pweights = (const float*)d_in[3];
  const float* Wfc      = (const float*)d_in[4];
  float* out = (float*)d_out;

  const int n_nodes = in_sizes[0] / HIDDEN;          // 100000
  const int gblocks = (n_nodes + BN - 1) / BN;       // 3125

  // ws layout: [Yc u8 NCHUNK*N*REC = N*256][sYh fp16 N*2][wfc bf16 128*256]
  char* ws = (char*)d_ws;
  unsigned char* Yc = (unsigned char*)ws;
  unsigned short* sYh = (unsigned short*)(ws + (size_t)n_nodes * 256);
  unsigned short* wfc_bf = (unsigned short*)(ws + (size_t)n_nodes * 256
                                                + (size_t)n_nodes * ETYPES * sizeof(unsigned short));

  const int wfc4 = in_sizes[4] / 4;                  // 32768/4
  hipLaunchKernelGGL(cvt_bf16, dim3((wfc4 + 255) / 256), dim3(256), 0, stream,
                     Wfc, wfc_bf, wfc4);
  hipLaunchKernelGGL(gemm_quant, dim3(gblocks), dim3(256), 0, stream,
                     feats, wfc_bf, Yc, sYh, n_nodes);
  const int nblk = (n_nodes + 255) / 256;            // 391
  hipLaunchKernelGGL(impeller_gather, dim3(NCHUNK * nblk), dim3(256), 0, stream,
                     Yc, sYh, paths, ptypes, pweights, out, n_nodes);
}

// Round 3
// 188.449 us; speedup vs baseline: 2.0394x; 2.0394x over previous
//
#include <hip/hip_runtime.h>

#define HIDDEN 128
#define P_NUM 8
#define PLEN 4
#define ETYPES 2
#define BN 32                      // nodes per block (100000 = 3125*32, no tail)
#define APAD 8
#define AROW (2*HIDDEN + APAD)     // 264 bf16

typedef __attribute__((ext_vector_type(8))) short short8;
typedef __attribute__((ext_vector_type(4))) float floatx4;

__device__ __forceinline__ unsigned short f2bf(float x) {
  unsigned int u = __float_as_uint(x);
  u += 0x7FFFu + ((u >> 16) & 1u);
  return (unsigned short)(u >> 16);
}

// generic f32 -> bf16 (used for W_fc)
__global__ __launch_bounds__(256) void cvt_bf16(const float* __restrict__ in,
                                                unsigned short* __restrict__ out, int n4) {
  int i = blockIdx.x * blockDim.x + threadIdx.x;
  if (i < n4) {
    float4 f = ((const float4*)in)[i];
    ((ushort4*)out)[i] = make_ushort4(f2bf(f.x), f2bf(f.y), f2bf(f.z), f2bf(f.w));
  }
}

// feats f32 -> BIASED u8 (u = rint(x*127/absmax)+128) with per-row scale.
// 1 wave = 2 rows (32 lanes/row, 4 vals/lane). Biased-u8 -> decode is 1 v_cvt_f32_ubyte.
__global__ __launch_bounds__(256) void cvt_u8(const float* __restrict__ in,
                                              unsigned char* __restrict__ q,
                                              float* __restrict__ scales, int n_rows) {
  const int wavei = blockIdx.x * 4 + (threadIdx.x >> 6);
  const int lane = threadIdx.x & 63;
  const int row = wavei * 2 + (lane >> 5);
  const int l32 = lane & 31;
  if (row >= n_rows) return;
  float4 f = *(const float4*)(in + (size_t)row * HIDDEN + l32 * 4);
  float m = fmaxf(fmaxf(fabsf(f.x), fabsf(f.y)), fmaxf(fabsf(f.z), fabsf(f.w)));
  #pragma unroll
  for (int d = 1; d < 32; d <<= 1) m = fmaxf(m, __shfl_xor(m, d));
  float inv = (m > 0.f) ? 127.f / m : 0.f;
  int q0 = (int)rintf(f.x * inv) + 128, q1 = (int)rintf(f.y * inv) + 128;
  int q2 = (int)rintf(f.z * inv) + 128, q3 = (int)rintf(f.w * inv) + 128;
  unsigned int pack = (q0 & 0xFF) | ((q1 & 0xFF) << 8) | ((q2 & 0xFF) << 16) | ((q3 & 0xFF) << 24);
  ((unsigned int*)q)[(size_t)row * (HIDDEN / 4) + l32] = pack;
  if (l32 == 0) scales[row] = m / 127.f;
}

// Fused: type-specialized-wave gather (feats table, 12.8 MB) + in-block MFMA GEMM.
// Wave (e = wv>>1, half = wv&1) handles 16 nodes for edge type e only:
//   per 2-node iteration, 4 groups x 4 hops x 2 nodes = 32 random 128B rows in flight.
__global__ __launch_bounds__(256, 6) void impeller_fused(
    const unsigned char* __restrict__ feats_q,  // biased u8, N x 128
    const float* __restrict__ scales,           // f32, N
    const int* __restrict__ paths,
    const int* __restrict__ ptypes,
    const float* __restrict__ pweights,
    const unsigned short* __restrict__ wfc_bf,  // bf16, 128 x 256
    float* __restrict__ out,
    int n_nodes)
{
  __shared__ __align__(16) unsigned short A[BN * AROW];   // 16896 B only -> more blocks/CU

  const int tid = threadIdx.x;
  const int n0 = blockIdx.x * BN;
  const int wv = tid >> 6;
  const int lane = tid & 63;
  const int g = lane >> 4;          // group 0..3 (one path slot per group)
  const int r = lane & 15;          // dims [r*8, r*8+8)

  const int e = wv >> 1;            // this wave's edge type
  const int nh = (wv & 1) * 16;     // node half: local nodes nh..nh+15

  // ---- find this group's path(s) of type e: slot0 = g-th occurrence, slot1 = (g+4)-th ----
  int p0 = 0, p1 = 0, cnt = 0;
  #pragma unroll
  for (int p = 0; p < P_NUM; ++p) {
    const int t = ptypes[p];
    if (t == e) { if (cnt == g) p0 = p; if (cnt == g + 4) p1 = p; ++cnt; }
  }
  const bool v0 = (g < cnt);
  const bool v1 = (g + 4 < cnt);
  const bool has2 = (cnt > 4);                 // wave-uniform -> clean branch
  const float ic = (cnt > 0) ? 1.f / (float)cnt : 0.f;
  float cl0[PLEN], cl1[PLEN];
  #pragma unroll
  for (int l = 0; l < PLEN; ++l) {
    const float w = pweights[e * PLEN + l] * ic;
    cl0[l] = v0 ? w : 0.f;
    cl1[l] = v1 ? w : 0.f;
  }
  if (!v0) p0 = 0;
  if (!v1) p1 = 0;

  // ---- gather loop: 8 iterations x 2 nodes ----
  #pragma unroll 1
  for (int it = 0; it < 8; ++it) {
    const int nA = n0 + nh + it * 2;
    const int nB = nA + 1;

    const int4 iA = *(const int4*)&paths[((size_t)p0 * n_nodes + nA) * PLEN];
    const int4 iB = *(const int4*)&paths[((size_t)p0 * n_nodes + nB) * PLEN];
    const int ia[4] = {iA.x, iA.y, iA.z, iA.w};
    const int ib[4] = {iB.x, iB.y, iB.z, iB.w};

    // 32 row-loads in flight across the wave (4 groups x 4 hops x 2 nodes)
    uint2 fa[4], fb[4];
    float sa[4], sb[4];
    #pragma unroll
    for (int l = 0; l < PLEN; ++l) {
      fa[l] = *(const uint2*)(feats_q + (size_t)ia[l] * HIDDEN + r * 8);
      sa[l] = scales[ia[l]];
    }
    #pragma unroll
    for (int l = 0; l < PLEN; ++l) {
      fb[l] = *(const uint2*)(feats_q + (size_t)ib[l] * HIDDEN + r * 8);
      sb[l] = scales[ib[l]];
    }

    #pragma unroll
    for (int half = 0; half < 2; ++half) {
      const int nn = half ? nB : nA;
      float a[8] = {0.f, 0.f, 0.f, 0.f, 0.f, 0.f, 0.f, 0.f};
      float corr = 0.f;
      #pragma unroll
      for (int l = 0; l < PLEN; ++l) {
        const uint2 f = half ? fb[l] : fa[l];
        const float cs = (half ? cl0[l] * sb[l] : cl0[l] * sa[l]);
        corr += cs;
        a[0] += cs * (float)( f.x        & 0xFFu);
        a[1] += cs * (float)((f.x >>  8) & 0xFFu);
        a[2] += cs * (float)((f.x >> 16) & 0xFFu);
        a[3] += cs * (float)( f.x >> 24        );
        a[4] += cs * (float)( f.y        & 0xFFu);
        a[5] += cs * (float)((f.y >>  8) & 0xFFu);
        a[6] += cs * (float)((f.y >> 16) & 0xFFu);
        a[7] += cs * (float)( f.y >> 24        );
      }

      if (has2) {   // >4 paths of this type (generic case; cold for the given data)
        const int4 i2 = *(const int4*)&paths[((size_t)p1 * n_nodes + nn) * PLEN];
        const int i2a[4] = {i2.x, i2.y, i2.z, i2.w};
        #pragma unroll
        for (int l = 0; l < PLEN; ++l) {
          const uint2 f = *(const uint2*)(feats_q + (size_t)i2a[l] * HIDDEN + r * 8);
          const float cs = cl1[l] * scales[i2a[l]];
          corr += cs;
          a[0] += cs * (float)( f.x        & 0xFFu);
          a[1] += cs * (float)((f.x >>  8) & 0xFFu);
          a[2] += cs * (float)((f.x >> 16) & 0xFFu);
          a[3] += cs * (float)( f.x >> 24        );
          a[4] += cs * (float)( f.y        & 0xFFu);
          a[5] += cs * (float)((f.y >>  8) & 0xFFu);
          a[6] += cs * (float)((f.y >> 16) & 0xFFu);
          a[7] += cs * (float)( f.y >> 24        );
        }
      }

      // reduce across the 4 groups (same type, different paths)
      #pragma unroll
      for (int k = 0; k < 8; ++k) {
        a[k] += __shfl_xor(a[k], 16);
        a[k] += __shfl_xor(a[k], 32);
      }
      corr += __shfl_xor(corr, 16);
      corr += __shfl_xor(corr, 32);
      const float c128 = 128.f * corr;

      if (g == 0) {
        short8 u;
        #pragma unroll
        for (int k = 0; k < 8; ++k) u[k] = (short)f2bf(a[k] - c128);
        *(short8*)&A[(nn - n0) * AROW + e * HIDDEN + r * 8] = u;
      }
    }
  }
  __syncthreads();

  // ---- MFMA GEMM: out(32x128) = A(32x256) @ WfcBf^T(256x128) ---- (R0-proven)
  const int q = lane >> 4;
  const int rr = lane & 15;

  floatx4 acc[2][2];
  #pragma unroll
  for (int mt = 0; mt < 2; ++mt)
    #pragma unroll
    for (int jt = 0; jt < 2; ++jt)
      acc[mt][jt] = (floatx4){0.f, 0.f, 0.f, 0.f};

  #pragma unroll
  for (int kk = 0; kk < 8; ++kk) {
    short8 af[2];
    #pragma unroll
    for (int mt = 0; mt < 2; ++mt)
      af[mt] = *(const short8*)&A[(mt * 16 + rr) * AROW + kk * 32 + q * 8];

    short8 bfr[2];
    #pragma unroll
    for (int jt = 0; jt < 2; ++jt) {
      const int j = wv * 32 + jt * 16 + rr;                  // output col = Wfc row
      bfr[jt] = *(const short8*)&wfc_bf[(size_t)j * (ETYPES * HIDDEN) + kk * 32 + q * 8];
    }

    #pragma unroll
    for (int mt = 0; mt < 2; ++mt)
      #pragma unroll
      for (int jt = 0; jt < 2; ++jt)
        acc[mt][jt] = __builtin_amdgcn_mfma_f32_16x16x32_bf16(af[mt], bfr[jt], acc[mt][jt], 0, 0, 0);
  }

  #pragma unroll
  for (int mt = 0; mt < 2; ++mt) {
    const int node_base = n0 + mt * 16 + q * 4;
    #pragma unroll
    for (int jt = 0; jt < 2; ++jt) {
      const int j = wv * 32 + jt * 16 + rr;
      #pragma unroll
      for (int reg = 0; reg < 4; ++reg) {
        const int nn = node_base + reg;
        if (nn < n_nodes) out[(size_t)nn * HIDDEN + j] = fmaxf(acc[mt][jt][reg], 0.f);
      }
    }
  }
}

extern "C" void kernel_launch(void* const* d_in, const int* in_sizes, int n_in,
                              void* d_out, int out_size, void* d_ws, size_t ws_size,
                              hipStream_t stream) {
  const float* feats    = (const float*)d_in[0];
  const int*   paths    = (const int*)d_in[1];
  const int*   ptypes   = (const int*)d_in[2];
  const float* pweights = (const float*)d_in[3];
  const float* Wfc      = (const float*)d_in[4];
  float* out = (float*)d_out;

  const int n_nodes = in_sizes[0] / HIDDEN;          // 100000
  const int blocks = (n_nodes + BN - 1) / BN;

  // ws layout: [feats_q u8 N*128][scales f32 N][wfc bf16 128*256]
  char* ws = (char*)d_ws;
  unsigned char* feats_q = (unsigned char*)ws;
  float* scales = (float*)(ws + (size_t)n_nodes * HIDDEN);
  unsigned short* wfc_bf = (unsigned short*)(ws + (size_t)n_nodes * HIDDEN
                                                + (size_t)n_nodes * sizeof(float));

  hipLaunchKernelGGL(cvt_u8, dim3((n_nodes + 7) / 8), dim3(256), 0, stream,
                     feats, feats_q, scales, n_nodes);
  const int wfc4 = in_sizes[4] / 4;                  // 32768/4
  hipLaunchKernelGGL(cvt_bf16, dim3((wfc4 + 255) / 256), dim3(256), 0, stream,
                     Wfc, wfc_bf, wfc4);
  hipLaunchKernelGGL(impeller_fused, dim3(blocks), dim3(256), 0, stream,
                     feats_q, scales, paths, ptypes, pweights, wfc_bf, out, n_nodes);
}

// Round 4
// 188.306 us; speedup vs baseline: 2.0409x; 1.0008x over previous
//
#include <hip/hip_runtime.h>

#define HIDDEN 128
#define P_NUM 8
#define PLEN 4
#define ETYPES 2
#define BN 32                      // nodes per block (100000 = 3125*32, no tail)
#define APAD 8
#define AROW (2*HIDDEN + APAD)     // 264 bf16

typedef __attribute__((ext_vector_type(8))) short short8;
typedef __attribute__((ext_vector_type(4))) float floatx4;

__device__ __forceinline__ unsigned short f2bf(float x) {
  unsigned int u = __float_as_uint(x);
  u += 0x7FFFu + ((u >> 16) & 1u);
  return (unsigned short)(u >> 16);
}

// generic f32 -> bf16 (used for W_fc)
__global__ __launch_bounds__(256) void cvt_bf16(const float* __restrict__ in,
                                                unsigned short* __restrict__ out, int n4) {
  int i = blockIdx.x * blockDim.x + threadIdx.x;
  if (i < n4) {
    float4 f = ((const float4*)in)[i];
    ((ushort4*)out)[i] = make_ushort4(f2bf(f.x), f2bf(f.y), f2bf(f.z), f2bf(f.w));
  }
}

// feats f32 -> BIASED u8 (u = rint(x*127/absmax)+128) with per-row scale.
__global__ __launch_bounds__(256) void cvt_u8(const float* __restrict__ in,
                                              unsigned char* __restrict__ q,
                                              float* __restrict__ scales, int n_rows) {
  const int wavei = blockIdx.x * 4 + (threadIdx.x >> 6);
  const int lane = threadIdx.x & 63;
  const int row = wavei * 2 + (lane >> 5);
  const int l32 = lane & 31;
  if (row >= n_rows) return;
  float4 f = *(const float4*)(in + (size_t)row * HIDDEN + l32 * 4);
  float m = fmaxf(fmaxf(fabsf(f.x), fabsf(f.y)), fmaxf(fabsf(f.z), fabsf(f.w)));
  #pragma unroll
  for (int d = 1; d < 32; d <<= 1) m = fmaxf(m, __shfl_xor(m, d));
  float inv = (m > 0.f) ? 127.f / m : 0.f;
  int q0 = (int)rintf(f.x * inv) + 128, q1 = (int)rintf(f.y * inv) + 128;
  int q2 = (int)rintf(f.z * inv) + 128, q3 = (int)rintf(f.w * inv) + 128;
  unsigned int pack = (q0 & 0xFF) | ((q1 & 0xFF) << 8) | ((q2 & 0xFF) << 16) | ((q3 & 0xFF) << 24);
  ((unsigned int*)q)[(size_t)row * (HIDDEN / 4) + l32] = pack;
  if (l32 == 0) scales[row] = m / 127.f;
}

// Fused: type-specialized-wave gather + in-block MFMA GEMM.
// Fast path is a depth-2 software pipeline: idx one iteration ahead of rows,
// rows one iteration ahead of consume; issue order idx(it+2) -> rows(it+1) -> consume(it)
// keeps every s_waitcnt a COUNTED vmcnt (no full drains) -> ~32 random lines in flight/wave.
__global__ __launch_bounds__(256, 4) void impeller_fused(
    const unsigned char* __restrict__ feats_q,  // biased u8, N x 128
    const float* __restrict__ scales,           // f32, N
    const int* __restrict__ paths,
    const int* __restrict__ ptypes,
    const float* __restrict__ pweights,
    const unsigned short* __restrict__ wfc_bf,  // bf16, 128 x 256
    float* __restrict__ out,
    int n_nodes)
{
  __shared__ __align__(16) unsigned short A[BN * AROW];   // 16896 B

  const int tid = threadIdx.x;
  const int n0 = blockIdx.x * BN;
  const int wv = tid >> 6;
  const int lane = tid & 63;
  const int g = lane >> 4;          // group 0..3 (one path slot per group)
  const int r = lane & 15;          // dims [r*8, r*8+8)

  const int e = wv >> 1;            // this wave's edge type
  const int nh = (wv & 1) * 16;     // local node half: nh..nh+15

  // ---- this group's path(s) of type e ----
  int p0 = 0, p1 = 0, cnt = 0;
  #pragma unroll
  for (int p = 0; p < P_NUM; ++p) {
    const int t = ptypes[p];
    if (t == e) { if (cnt == g) p0 = p; if (cnt == g + 4) p1 = p; ++cnt; }
  }
  const bool v0 = (g < cnt);
  const float ic = (cnt > 0) ? 1.f / (float)cnt : 0.f;
  float cl0[PLEN];
  #pragma unroll
  for (int l = 0; l < PLEN; ++l) {
    const float w = pweights[e * PLEN + l] * ic;
    cl0[l] = v0 ? w : 0.f;
  }
  if (!v0) p0 = 0;

  const int* pbase = paths + (size_t)p0 * n_nodes * PLEN;
  const int nodebase = n0 + nh;

  if (cnt <= 4) {
    // ================= fast path: pipelined gather =================
    uint2 fa0[4], fb0[4], fa1[4], fb1[4];
    float sa0[4], sb0[4], sa1[4], sb1[4];
    int4 iAe, iBe, iAo, iBo;

    auto LOAD_IDX = [&](int it, int4 &iA, int4 &iB) {
      const int nn = nodebase + it * 2;
      iA = *(const int4*)&pbase[(size_t)nn * PLEN];
      iB = *(const int4*)&pbase[(size_t)(nn + 1) * PLEN];
    };
    auto LOAD_ROWS = [&](const int4 &iA, const int4 &iB,
                         uint2 (&fa)[4], uint2 (&fb)[4], float (&sa)[4], float (&sb)[4]) {
      const int ia[4] = {iA.x, iA.y, iA.z, iA.w};
      const int ib[4] = {iB.x, iB.y, iB.z, iB.w};
      #pragma unroll
      for (int l = 0; l < PLEN; ++l) {
        fa[l] = *(const uint2*)(feats_q + (size_t)ia[l] * HIDDEN + r * 8);
        sa[l] = scales[ia[l]];
      }
      #pragma unroll
      for (int l = 0; l < PLEN; ++l) {
        fb[l] = *(const uint2*)(feats_q + (size_t)ib[l] * HIDDEN + r * 8);
        sb[l] = scales[ib[l]];
      }
    };
    auto CONSUME = [&](int it, const uint2 (&fa)[4], const uint2 (&fb)[4],
                       const float (&sa)[4], const float (&sb)[4]) {
      #pragma unroll
      for (int half = 0; half < 2; ++half) {
        float a[8] = {0.f, 0.f, 0.f, 0.f, 0.f, 0.f, 0.f, 0.f};
        float corr = 0.f;
        #pragma unroll
        for (int l = 0; l < PLEN; ++l) {
          const uint2 f = half ? fb[l] : fa[l];
          const float cs = cl0[l] * (half ? sb[l] : sa[l]);
          corr += cs;
          a[0] += cs * (float)( f.x        & 0xFFu);
          a[1] += cs * (float)((f.x >>  8) & 0xFFu);
          a[2] += cs * (float)((f.x >> 16) & 0xFFu);
          a[3] += cs * (float)( f.x >> 24        );
          a[4] += cs * (float)( f.y        & 0xFFu);
          a[5] += cs * (float)((f.y >>  8) & 0xFFu);
          a[6] += cs * (float)((f.y >> 16) & 0xFFu);
          a[7] += cs * (float)( f.y >> 24        );
        }
        #pragma unroll
        for (int k = 0; k < 8; ++k) {
          a[k] += __shfl_xor(a[k], 16);
          a[k] += __shfl_xor(a[k], 32);
        }
        corr += __shfl_xor(corr, 16);
        corr += __shfl_xor(corr, 32);
        const float c128 = 128.f * corr;
        if (g == 0) {
          short8 u;
          #pragma unroll
          for (int k = 0; k < 8; ++k) u[k] = (short)f2bf(a[k] - c128);
          *(short8*)&A[(nh + it * 2 + half) * AROW + e * HIDDEN + r * 8] = u;
        }
      }
    };

    // prologue
    LOAD_IDX(0, iAe, iBe);
    LOAD_IDX(1, iAo, iBo);
    LOAD_ROWS(iAe, iBe, fa0, fb0, sa0, sb0);   // one-time drain of idx0/idx1

    #pragma unroll 1
    for (int ith = 0; ith < 3; ++ith) {
      LOAD_IDX(2 * ith + 2, iAe, iBe);                     // idx two ahead (issued BEFORE rows)
      LOAD_ROWS(iAo, iBo, fa1, fb1, sa1, sb1);             // rows(it+1); counted wait on idx(it+1)
      __builtin_amdgcn_sched_barrier(0);                   // pin loads above consume
      CONSUME(2 * ith, fa0, fb0, sa0, sb0);                // counted wait; 18 ops stay in flight
      LOAD_IDX(2 * ith + 3, iAo, iBo);
      LOAD_ROWS(iAe, iBe, fa0, fb0, sa0, sb0);
      __builtin_amdgcn_sched_barrier(0);
      CONSUME(2 * ith + 1, fa1, fb1, sa1, sb1);
    }
    // epilogue: rows(7) then last two consumes
    LOAD_ROWS(iAo, iBo, fa1, fb1, sa1, sb1);
    __builtin_amdgcn_sched_barrier(0);
    CONSUME(6, fa0, fb0, sa0, sb0);
    CONSUME(7, fa1, fb1, sa1, sb1);
  } else {
    // ================= generic fallback (cnt > 4): R3-proven structure =================
    const bool v1 = (g + 4 < cnt);
    float cl1[PLEN];
    #pragma unroll
    for (int l = 0; l < PLEN; ++l) {
      const float w = pweights[e * PLEN + l] * ic;
      cl1[l] = v1 ? w : 0.f;
    }
    if (!v1) p1 = 0;

    #pragma unroll 1
    for (int it = 0; it < 8; ++it) {
      const int nA = nodebase + it * 2;
      const int nB = nA + 1;
      const int4 iA = *(const int4*)&pbase[(size_t)nA * PLEN];
      const int4 iB = *(const int4*)&pbase[(size_t)nB * PLEN];
      const int ia[4] = {iA.x, iA.y, iA.z, iA.w};
      const int ib[4] = {iB.x, iB.y, iB.z, iB.w};
      uint2 fa[4], fb[4];
      float sa[4], sb[4];
      #pragma unroll
      for (int l = 0; l < PLEN; ++l) {
        fa[l] = *(const uint2*)(feats_q + (size_t)ia[l] * HIDDEN + r * 8);
        sa[l] = scales[ia[l]];
      }
      #pragma unroll
      for (int l = 0; l < PLEN; ++l) {
        fb[l] = *(const uint2*)(feats_q + (size_t)ib[l] * HIDDEN + r * 8);
        sb[l] = scales[ib[l]];
      }
      #pragma unroll
      for (int half = 0; half < 2; ++half) {
        const int nn = half ? nB : nA;
        float a[8] = {0.f, 0.f, 0.f, 0.f, 0.f, 0.f, 0.f, 0.f};
        float corr = 0.f;
        #pragma unroll
        for (int l = 0; l < PLEN; ++l) {
          const uint2 f = half ? fb[l] : fa[l];
          const float cs = cl0[l] * (half ? sb[l] : sa[l]);
          corr += cs;
          a[0] += cs * (float)( f.x        & 0xFFu);
          a[1] += cs * (float)((f.x >>  8) & 0xFFu);
          a[2] += cs * (float)((f.x >> 16) & 0xFFu);
          a[3] += cs * (float)( f.x >> 24        );
          a[4] += cs * (float)( f.y        & 0xFFu);
          a[5] += cs * (float)((f.y >>  8) & 0xFFu);
          a[6] += cs * (float)((f.y >> 16) & 0xFFu);
          a[7] += cs * (float)( f.y >> 24        );
        }
        {
          const int4 i2 = *(const int4*)&paths[((size_t)p1 * n_nodes + nn) * PLEN];
          const int i2a[4] = {i2.x, i2.y, i2.z, i2.w};
          #pragma unroll
          for (int l = 0; l < PLEN; ++l) {
            const uint2 f = *(const uint2*)(feats_q + (size_t)i2a[l] * HIDDEN + r * 8);
            const float cs = cl1[l] * scales[i2a[l]];
            corr += cs;
            a[0] += cs * (float)( f.x        & 0xFFu);
            a[1] += cs * (float)((f.x >>  8) & 0xFFu);
            a[2] += cs * (float)((f.x >> 16) & 0xFFu);
            a[3] += cs * (float)( f.x >> 24        );
            a[4] += cs * (float)( f.y        & 0xFFu);
            a[5] += cs * (float)((f.y >>  8) & 0xFFu);
            a[6] += cs * (float)((f.y >> 16) & 0xFFu);
            a[7] += cs * (float)( f.y >> 24        );
          }
        }
        #pragma unroll
        for (int k = 0; k < 8; ++k) {
          a[k] += __shfl_xor(a[k], 16);
          a[k] += __shfl_xor(a[k], 32);
        }
        corr += __shfl_xor(corr, 16);
        corr += __shfl_xor(corr, 32);
        const float c128 = 128.f * corr;
        if (g == 0) {
          short8 u;
          #pragma unroll
          for (int k = 0; k < 8; ++k) u[k] = (short)f2bf(a[k] - c128);
          *(short8*)&A[(nh + it * 2 + half) * AROW + e * HIDDEN + r * 8] = u;
        }
      }
    }
  }
  __syncthreads();

  // ---- MFMA GEMM: out(32x128) = A(32x256) @ WfcBf^T(256x128) ---- (R0-proven)
  const int q = lane >> 4;
  const int rr = lane & 15;

  floatx4 acc[2][2];
  #pragma unroll
  for (int mt = 0; mt < 2; ++mt)
    #pragma unroll
    for (int jt = 0; jt < 2; ++jt)
      acc[mt][jt] = (floatx4){0.f, 0.f, 0.f, 0.f};

  #pragma unroll
  for (int kk = 0; kk < 8; ++kk) {
    short8 af[2];
    #pragma unroll
    for (int mt = 0; mt < 2; ++mt)
      af[mt] = *(const short8*)&A[(mt * 16 + rr) * AROW + kk * 32 + q * 8];

    short8 bfr[2];
    #pragma unroll
    for (int jt = 0; jt < 2; ++jt) {
      const int j = wv * 32 + jt * 16 + rr;                  // output col = Wfc row
      bfr[jt] = *(const short8*)&wfc_bf[(size_t)j * (ETYPES * HIDDEN) + kk * 32 + q * 8];
    }

    #pragma unroll
    for (int mt = 0; mt < 2; ++mt)
      #pragma unroll
      for (int jt = 0; jt < 2; ++jt)
        acc[mt][jt] = __builtin_amdgcn_mfma_f32_16x16x32_bf16(af[mt], bfr[jt], acc[mt][jt], 0, 0, 0);
  }

  #pragma unroll
  for (int mt = 0; mt < 2; ++mt) {
    const int node_base = n0 + mt * 16 + q * 4;
    #pragma unroll
    for (int jt = 0; jt < 2; ++jt) {
      const int j = wv * 32 + jt * 16 + rr;
      #pragma unroll
      for (int reg = 0; reg < 4; ++reg) {
        const int nn = node_base + reg;
        if (nn < n_nodes) out[(size_t)nn * HIDDEN + j] = fmaxf(acc[mt][jt][reg], 0.f);
      }
    }
  }
}

extern "C" void kernel_launch(void* const* d_in, const int* in_sizes, int n_in,
                              void* d_out, int out_size, void* d_ws, size_t ws_size,
                              hipStream_t stream) {
  const float* feats    = (const float*)d_in[0];
  const int*   paths    = (const int*)d_in[1];
  const int*   ptypes   = (const int*)d_in[2];
  const float* pweights = (const float*)d_in[3];
  const float* Wfc      = (const float*)d_in[4];
  float* out = (float*)d_out;

  const int n_nodes = in_sizes[0] / HIDDEN;          // 100000
  const int blocks = (n_nodes + BN - 1) / BN;

  // ws layout: [feats_q u8 N*128][scales f32 N][wfc bf16 128*256]
  char* ws = (char*)d_ws;
  unsigned char* feats_q = (unsigned char*)ws;
  float* scales = (float*)(ws + (size_t)n_nodes * HIDDEN);
  unsigned short* wfc_bf = (unsigned short*)(ws + (size_t)n_nodes * HIDDEN
                                                + (size_t)n_nodes * sizeof(float));

  hipLaunchKernelGGL(cvt_u8, dim3((n_nodes + 7) / 8), dim3(256), 0, stream,
                     feats, feats_q, scales, n_nodes);
  const int wfc4 = in_sizes[4] / 4;                  // 32768/4
  hipLaunchKernelGGL(cvt_bf16, dim3((wfc4 + 255) / 256), dim3(256), 0, stream,
                     Wfc, wfc_bf, wfc4);
  hipLaunchKernelGGL(impeller_fused, dim3(blocks), dim3(256), 0, stream,
                     feats_q, scales, paths, ptypes, pweights, wfc_bf, out, n_nodes);
}

// Round 5
// 184.462 us; speedup vs baseline: 2.0834x; 1.0208x over previous
//
#include <hip/hip_runtime.h>

#define HIDDEN 128
#define P_NUM 8
#define PLEN 4
#define ETYPES 2
#define BN 32                      // nodes per block (100000 = 3125*32, no tail)
#define APAD 8
#define AROW (2*HIDDEN + APAD)     // 264 bf16

typedef __attribute__((ext_vector_type(8))) short short8;
typedef __attribute__((ext_vector_type(4))) float floatx4;

__device__ __forceinline__ unsigned short f2bf(float x) {
  unsigned int u = __float_as_uint(x);
  u += 0x7FFFu + ((u >> 16) & 1u);
  return (unsigned short)(u >> 16);
}

// generic f32 -> bf16 (used for W_fc)
__global__ __launch_bounds__(256) void cvt_bf16(const float* __restrict__ in,
                                                unsigned short* __restrict__ out, int n4) {
  int i = blockIdx.x * blockDim.x + threadIdx.x;
  if (i < n4) {
    float4 f = ((const float4*)in)[i];
    ((ushort4*)out)[i] = make_ushort4(f2bf(f.x), f2bf(f.y), f2bf(f.z), f2bf(f.w));
  }
}

// feats f32 -> BIASED u8 (u = rint(x*127/absmax)+128) with per-row scale.
__global__ __launch_bounds__(256) void cvt_u8(const float* __restrict__ in,
                                              unsigned char* __restrict__ q,
                                              float* __restrict__ scales, int n_rows) {
  const int wavei = blockIdx.x * 4 + (threadIdx.x >> 6);
  const int lane = threadIdx.x & 63;
  const int row = wavei * 2 + (lane >> 5);
  const int l32 = lane & 31;
  if (row >= n_rows) return;
  float4 f = *(const float4*)(in + (size_t)row * HIDDEN + l32 * 4);
  float m = fmaxf(fmaxf(fabsf(f.x), fabsf(f.y)), fmaxf(fabsf(f.z), fabsf(f.w)));
  #pragma unroll
  for (int d = 1; d < 32; d <<= 1) m = fmaxf(m, __shfl_xor(m, d));
  float inv = (m > 0.f) ? 127.f / m : 0.f;
  int q0 = (int)rintf(f.x * inv) + 128, q1 = (int)rintf(f.y * inv) + 128;
  int q2 = (int)rintf(f.z * inv) + 128, q3 = (int)rintf(f.w * inv) + 128;
  unsigned int pack = (q0 & 0xFF) | ((q1 & 0xFF) << 8) | ((q2 & 0xFF) << 16) | ((q3 & 0xFF) << 24);
  ((unsigned int*)q)[(size_t)row * (HIDDEN / 4) + l32] = pack;
  if (l32 == 0) scales[row] = m / 127.f;
}

// Fused: type-specialized-wave gather + in-block MFMA GEMM.
// Row gathers stay on the vector path (4 groups x 16 lanes -> 4 lines/instr).
// Per-row SCALES move to the SCALAR path: idx is group-uniform, so readlane at
// lanes 0/16/32/48 + s_load_dword keeps 3.2M scale loads OFF the vector miss queue.
__global__ __launch_bounds__(256, 6) void impeller_fused(
    const unsigned char* __restrict__ feats_q,  // biased u8, N x 128
    const float* __restrict__ scales,           // f32, N
    const int* __restrict__ paths,
    const int* __restrict__ ptypes,
    const float* __restrict__ pweights,
    const unsigned short* __restrict__ wfc_bf,  // bf16, 128 x 256
    float* __restrict__ out,
    int n_nodes)
{
  __shared__ __align__(16) unsigned short A[BN * AROW];   // 16896 B

  const int tid = threadIdx.x;
  const int n0 = blockIdx.x * BN;
  const int wv = tid >> 6;
  const int lane = tid & 63;
  const int g = lane >> 4;          // group 0..3 (one path slot per group)
  const int r = lane & 15;          // dims [r*8, r*8+8)

  const int e = wv >> 1;            // this wave's edge type
  const int nh = (wv & 1) * 16;     // local node half: nh..nh+15

  // ---- this group's path(s) of type e ----
  int p0 = 0, p1 = 0, cnt = 0;
  #pragma unroll
  for (int p = 0; p < P_NUM; ++p) {
    const int t = ptypes[p];
    if (t == e) { if (cnt == g) p0 = p; if (cnt == g + 4) p1 = p; ++cnt; }
  }
  const bool v0 = (g < cnt);
  const float ic = (cnt > 0) ? 1.f / (float)cnt : 0.f;
  float cl0[PLEN];
  #pragma unroll
  for (int l = 0; l < PLEN; ++l) {
    const float w = pweights[e * PLEN + l] * ic;
    cl0[l] = v0 ? w : 0.f;
  }
  if (!v0) p0 = 0;

  const int* pbase = paths + (size_t)p0 * n_nodes * PLEN;
  const int nodebase = n0 + nh;

  // lane-group select masks (hoisted; used for SGPR->VGPR scale select)
  const bool m0 = (g == 0), m1 = (g == 1), m2 = (g == 2);

  if (cnt <= 4) {
    // ================= fast path =================
    int4 iA = *(const int4*)&pbase[(size_t)nodebase * PLEN];
    int4 iB = *(const int4*)&pbase[(size_t)(nodebase + 1) * PLEN];

    #pragma unroll 1
    for (int it = 0; it < 8; ++it) {
      // prefetch next iteration's indices (stays in flight across the consume)
      int4 iA_n = iA, iB_n = iB;
      if (it < 7) {
        const int nn = nodebase + (it + 1) * 2;
        iA_n = *(const int4*)&pbase[(size_t)nn * PLEN];
        iB_n = *(const int4*)&pbase[(size_t)(nn + 1) * PLEN];
      }

      const int ia[4] = {iA.x, iA.y, iA.z, iA.w};
      const int ib[4] = {iB.x, iB.y, iB.z, iB.w};

      // ---- scalar-path scale loads: 32 s_load_dword (uniform via readlane) ----
      float cA[PLEN][4], cB[PLEN][4];
      #pragma unroll
      for (int l = 0; l < PLEN; ++l) {
        cA[l][0] = scales[(unsigned)__builtin_amdgcn_readlane(ia[l], 0)];
        cA[l][1] = scales[(unsigned)__builtin_amdgcn_readlane(ia[l], 16)];
        cA[l][2] = scales[(unsigned)__builtin_amdgcn_readlane(ia[l], 32)];
        cA[l][3] = scales[(unsigned)__builtin_amdgcn_readlane(ia[l], 48)];
      }
      #pragma unroll
      for (int l = 0; l < PLEN; ++l) {
        cB[l][0] = scales[(unsigned)__builtin_amdgcn_readlane(ib[l], 0)];
        cB[l][1] = scales[(unsigned)__builtin_amdgcn_readlane(ib[l], 16)];
        cB[l][2] = scales[(unsigned)__builtin_amdgcn_readlane(ib[l], 32)];
        cB[l][3] = scales[(unsigned)__builtin_amdgcn_readlane(ib[l], 48)];
      }

      // ---- vector-path row loads: 16 x 8B, 4 lines/instr ----
      uint2 fa[4], fb[4];
      #pragma unroll
      for (int l = 0; l < PLEN; ++l)
        fa[l] = *(const uint2*)(feats_q + (size_t)ia[l] * HIDDEN + r * 8);
      #pragma unroll
      for (int l = 0; l < PLEN; ++l)
        fb[l] = *(const uint2*)(feats_q + (size_t)ib[l] * HIDDEN + r * 8);

      // per-lane scale select from the 4 group scalars (3 cndmask each)
      float scA[PLEN], scB[PLEN];
      #pragma unroll
      for (int l = 0; l < PLEN; ++l) {
        scA[l] = m0 ? cA[l][0] : (m1 ? cA[l][1] : (m2 ? cA[l][2] : cA[l][3]));
        scB[l] = m0 ? cB[l][0] : (m1 ? cB[l][1] : (m2 ? cB[l][2] : cB[l][3]));
      }

      #pragma unroll
      for (int half = 0; half < 2; ++half) {
        float a[8] = {0.f, 0.f, 0.f, 0.f, 0.f, 0.f, 0.f, 0.f};
        float corr = 0.f;
        #pragma unroll
        for (int l = 0; l < PLEN; ++l) {
          const uint2 f = half ? fb[l] : fa[l];
          const float cs = cl0[l] * (half ? scB[l] : scA[l]);
          corr += cs;
          a[0] += cs * (float)( f.x        & 0xFFu);
          a[1] += cs * (float)((f.x >>  8) & 0xFFu);
          a[2] += cs * (float)((f.x >> 16) & 0xFFu);
          a[3] += cs * (float)( f.x >> 24        );
          a[4] += cs * (float)( f.y        & 0xFFu);
          a[5] += cs * (float)((f.y >>  8) & 0xFFu);
          a[6] += cs * (float)((f.y >> 16) & 0xFFu);
          a[7] += cs * (float)( f.y >> 24        );
        }
        #pragma unroll
        for (int k = 0; k < 8; ++k) {
          a[k] += __shfl_xor(a[k], 16);
          a[k] += __shfl_xor(a[k], 32);
        }
        corr += __shfl_xor(corr, 16);
        corr += __shfl_xor(corr, 32);
        const float c128 = 128.f * corr;
        if (g == 0) {
          short8 u;
          #pragma unroll
          for (int k = 0; k < 8; ++k) u[k] = (short)f2bf(a[k] - c128);
          *(short8*)&A[(nh + it * 2 + half) * AROW + e * HIDDEN + r * 8] = u;
        }
      }

      iA = iA_n; iB = iB_n;
    }
  } else {
    // ================= generic fallback (cnt > 4): R3-proven structure =================
    const bool v1 = (g + 4 < cnt);
    float cl1[PLEN];
    #pragma unroll
    for (int l = 0; l < PLEN; ++l) {
      const float w = pweights[e * PLEN + l] * ic;
      cl1[l] = v1 ? w : 0.f;
    }
    if (!v1) p1 = 0;

    #pragma unroll 1
    for (int it = 0; it < 8; ++it) {
      const int nA = nodebase + it * 2;
      const int nB = nA + 1;
      const int4 iA = *(const int4*)&pbase[(size_t)nA * PLEN];
      const int4 iB = *(const int4*)&pbase[(size_t)nB * PLEN];
      const int ia[4] = {iA.x, iA.y, iA.z, iA.w};
      const int ib[4] = {iB.x, iB.y, iB.z, iB.w};
      uint2 fa[4], fb[4];
      float sa[4], sb[4];
      #pragma unroll
      for (int l = 0; l < PLEN; ++l) {
        fa[l] = *(const uint2*)(feats_q + (size_t)ia[l] * HIDDEN + r * 8);
        sa[l] = scales[ia[l]];
      }
      #pragma unroll
      for (int l = 0; l < PLEN; ++l) {
        fb[l] = *(const uint2*)(feats_q + (size_t)ib[l] * HIDDEN + r * 8);
        sb[l] = scales[ib[l]];
      }
      #pragma unroll
      for (int half = 0; half < 2; ++half) {
        const int nn = half ? nB : nA;
        float a[8] = {0.f, 0.f, 0.f, 0.f, 0.f, 0.f, 0.f, 0.f};
        float corr = 0.f;
        #pragma unroll
        for (int l = 0; l < PLEN; ++l) {
          const uint2 f = half ? fb[l] : fa[l];
          const float cs = cl0[l] * (half ? sb[l] : sa[l]);
          corr += cs;
          a[0] += cs * (float)( f.x        & 0xFFu);
          a[1] += cs * (float)((f.x >>  8) & 0xFFu);
          a[2] += cs * (float)((f.x >> 16) & 0xFFu);
          a[3] += cs * (float)( f.x >> 24        );
          a[4] += cs * (float)( f.y        & 0xFFu);
          a[5] += cs * (float)((f.y >>  8) & 0xFFu);
          a[6] += cs * (float)((f.y >> 16) & 0xFFu);
          a[7] += cs * (float)( f.y >> 24        );
        }
        {
          const int4 i2 = *(const int4*)&paths[((size_t)p1 * n_nodes + nn) * PLEN];
          const int i2a[4] = {i2.x, i2.y, i2.z, i2.w};
          #pragma unroll
          for (int l = 0; l < PLEN; ++l) {
            const uint2 f = *(const uint2*)(feats_q + (size_t)i2a[l] * HIDDEN + r * 8);
            const float cs = cl1[l] * scales[i2a[l]];
            corr += cs;
            a[0] += cs * (float)( f.x        & 0xFFu);
            a[1] += cs * (float)((f.x >>  8) & 0xFFu);
            a[2] += cs * (float)((f.x >> 16) & 0xFFu);
            a[3] += cs * (float)( f.x >> 24        );
            a[4] += cs * (float)( f.y        & 0xFFu);
            a[5] += cs * (float)((f.y >>  8) & 0xFFu);
            a[6] += cs * (float)((f.y >> 16) & 0xFFu);
            a[7] += cs * (float)( f.y >> 24        );
          }
        }
        #pragma unroll
        for (int k = 0; k < 8; ++k) {
          a[k] += __shfl_xor(a[k], 16);
          a[k] += __shfl_xor(a[k], 32);
        }
        corr += __shfl_xor(corr, 16);
        corr += __shfl_xor(corr, 32);
        const float c128 = 128.f * corr;
        if (g == 0) {
          short8 u;
          #pragma unroll
          for (int k = 0; k < 8; ++k) u[k] = (short)f2bf(a[k] - c128);
          *(short8*)&A[(nh + it * 2 + half) * AROW + e * HIDDEN + r * 8] = u;
        }
      }
    }
  }
  __syncthreads();

  // ---- MFMA GEMM: out(32x128) = A(32x256) @ WfcBf^T(256x128) ---- (R0-proven)
  const int q = lane >> 4;
  const int rr = lane & 15;

  floatx4 acc[2][2];
  #pragma unroll
  for (int mt = 0; mt < 2; ++mt)
    #pragma unroll
    for (int jt = 0; jt < 2; ++jt)
      acc[mt][jt] = (floatx4){0.f, 0.f, 0.f, 0.f};

  #pragma unroll
  for (int kk = 0; kk < 8; ++kk) {
    short8 af[2];
    #pragma unroll
    for (int mt = 0; mt < 2; ++mt)
      af[mt] = *(const short8*)&A[(mt * 16 + rr) * AROW + kk * 32 + q * 8];

    short8 bfr[2];
    #pragma unroll
    for (int jt = 0; jt < 2; ++jt) {
      const int j = wv * 32 + jt * 16 + rr;                  // output col = Wfc row
      bfr[jt] = *(const short8*)&wfc_bf[(size_t)j * (ETYPES * HIDDEN) + kk * 32 + q * 8];
    }

    #pragma unroll
    for (int mt = 0; mt < 2; ++mt)
      #pragma unroll
      for (int jt = 0; jt < 2; ++jt)
        acc[mt][jt] = __builtin_amdgcn_mfma_f32_16x16x32_bf16(af[mt], bfr[jt], acc[mt][jt], 0, 0, 0);
  }

  #pragma unroll
  for (int mt = 0; mt < 2; ++mt) {
    const int node_base = n0 + mt * 16 + q * 4;
    #pragma unroll
    for (int jt = 0; jt < 2; ++jt) {
      const int j = wv * 32 + jt * 16 + rr;
      #pragma unroll
      for (int reg = 0; reg < 4; ++reg) {
        const int nn = node_base + reg;
        if (nn < n_nodes) out[(size_t)nn * HIDDEN + j] = fmaxf(acc[mt][jt][reg], 0.f);
      }
    }
  }
}

extern "C" void kernel_launch(void* const* d_in, const int* in_sizes, int n_in,
                              void* d_out, int out_size, void* d_ws, size_t ws_size,
                              hipStream_t stream) {
  const float* feats    = (const float*)d_in[0];
  const int*   paths    = (const int*)d_in[1];
  const int*   ptypes   = (const int*)d_in[2];
  const float* pweights = (const float*)d_in[3];
  const float* Wfc      = (const float*)d_in[4];
  float* out = (float*)d_out;

  const int n_nodes = in_sizes[0] / HIDDEN;          // 100000
  const int blocks = (n_nodes + BN - 1) / BN;

  // ws layout: [feats_q u8 N*128][scales f32 N][wfc bf16 128*256]
  char* ws = (char*)d_ws;
  unsigned char* feats_q = (unsigned char*)ws;
  float* scales = (float*)(ws + (size_t)n_nodes * HIDDEN);
  unsigned short* wfc_bf = (unsigned short*)(ws + (size_t)n_nodes * HIDDEN
                                                + (size_t)n_nodes * sizeof(float));

  hipLaunchKernelGGL(cvt_u8, dim3((n_nodes + 7) / 8), dim3(256), 0, stream,
                     feats, feats_q, scales, n_nodes);
  const int wfc4 = in_sizes[4] / 4;                  // 32768/4
  hipLaunchKernelGGL(cvt_bf16, dim3((wfc4 + 255) / 256), dim3(256), 0, stream,
                     Wfc, wfc_bf, wfc4);
  hipLaunchKernelGGL(impeller_fused, dim3(blocks), dim3(256), 0, stream,
                     feats_q, scales, paths, ptypes, pweights, wfc_bf, out, n_nodes);
}